// Round 14
// baseline (1520.404 us; speedup 1.0000x reference)
//
#include <hip/hip_runtime.h>
#include <math.h>

// ============================================================================
// MultiViewPointAggregator — MFMA bf16, round 13b (compile fix of r13).
// PTS=16 (64 rows = 4 row-tiles): each B-fragment feeds 4 MFMAs. Register
// pressure engineered to the 128+128 split: qkv in 3 split passes (q/k/v),
// ff1 in 2 column-groups, rotation-style dist-1 pipelines (r10 pattern).
// MFMA out-head (r12) with 16 pooled rows filling the A-tile exactly.
// ============================================================================

typedef __attribute__((ext_vector_type(8))) short bf16x8;
typedef __attribute__((ext_vector_type(4))) float f32x4;

#define MFMA16(a, b, c) __builtin_amdgcn_mfma_f32_16x16x32_bf16((a), (b), (c), 0, 0, 0)

__device__ __forceinline__ unsigned short f2bf(float f) {
  unsigned u = __float_as_uint(f);
  return (unsigned short)((u + 0x7fffu + ((u >> 16) & 1u)) >> 16);  // RNE
}
__device__ __forceinline__ float bf2f(unsigned short u) {
  return __uint_as_float((unsigned)u << 16);
}

__device__ __forceinline__ bf16x8 ldAfrag(const unsigned short* base, int stride_us,
                                          int rt, int s, int l) {
  int row = rt * 16 + (l & 15);
  int slot = ((s << 2) + (l >> 4)) ^ (row & 7);
  return *(const bf16x8*)(base + row * stride_us + slot * 8);
}

// ---- ws segment offsets, in 64-lane*8-elem fragments (16B each) ----
#define FRAG_FP    0
#define FRAG_QKV0  3072
#define FRAG_QKV1  27648
#define FRAG_AO0   52224
#define FRAG_AO1   60416
#define FRAG_FF1_0 68608
#define FRAG_FF1_1 84992
#define FRAG_FF2_0 101376
#define FRAG_FF2_1 117760
#define FRAG_OUT   134144
#define FRAG_TOTAL 136192   // * 16B = 2179072 bytes

__global__ __launch_bounds__(256, 2)
void prepack_kernel(const float* __restrict__ fp_w, const float* __restrict__ qkv_w,
                    const float* __restrict__ ao_w, const float* __restrict__ ff1_w,
                    const float* __restrict__ ff2_w, const float* __restrict__ out_w,
                    unsigned short* __restrict__ ws) {
  int f = blockIdx.x * 256 + threadIdx.x;
  if (f >= FRAG_TOTAL) return;
  const float* W;
  int N, S, base;
  if (f < FRAG_QKV0)       { W = fp_w;            N = 256; S = 3;  base = FRAG_FP; }
  else if (f < FRAG_QKV1)  { W = qkv_w;           N = 768; S = 8;  base = FRAG_QKV0; }
  else if (f < FRAG_AO0)   { W = qkv_w + 196608;  N = 768; S = 8;  base = FRAG_QKV1; }
  else if (f < FRAG_AO1)   { W = ao_w;            N = 256; S = 8;  base = FRAG_AO0; }
  else if (f < FRAG_FF1_0) { W = ao_w + 65536;    N = 256; S = 8;  base = FRAG_AO1; }
  else if (f < FRAG_FF1_1) { W = ff1_w;           N = 512; S = 8;  base = FRAG_FF1_0; }
  else if (f < FRAG_FF2_0) { W = ff1_w + 131072;  N = 512; S = 8;  base = FRAG_FF1_1; }
  else if (f < FRAG_FF2_1) { W = ff2_w;           N = 256; S = 16; base = FRAG_FF2_0; }
  else if (f < FRAG_OUT)   { W = ff2_w + 131072;  N = 256; S = 16; base = FRAG_FF2_1; }
  else                     { W = out_w;           N = 64;  S = 8;  base = FRAG_OUT; }
  int r = f - base;
  int l = r & 63;
  int cs = r >> 6;
  int s = cs % S;
  int ct = cs / S;
  int k0 = s * 32 + (l >> 4) * 8;
  int col = ct * 16 + (l & 15);
  bf16x8 pk;
  #pragma unroll
  for (int j = 0; j < 8; ++j)
    pk[j] = (short)f2bf(W[(size_t)(k0 + j) * N + col]);
  *(bf16x8*)(ws + (size_t)f * 8) = pk;
}

#define PTS 16
#define NRT 4

__global__ __launch_bounds__(256, 2)
void mvpa_kernel(
    const float* __restrict__ xyz, const float* __restrict__ feat,
    const float* __restrict__ c2w, const float* __restrict__ intr,
    const int* __restrict__ time_ids, const float* __restrict__ view_emb,
    const float* __restrict__ pos_w, const float* __restrict__ pos_b,
    const float* __restrict__ fp_b, const float* __restrict__ qkv_b,
    const float* __restrict__ ao_b, const float* __restrict__ ln1_s,
    const float* __restrict__ ln1_b, const float* __restrict__ ff1_b,
    const float* __restrict__ ff2_b, const float* __restrict__ ln2_s,
    const float* __restrict__ ln2_b, const float* __restrict__ out_b,
    const unsigned short* __restrict__ ws, float* __restrict__ outp, int M)
{
  __shared__ __align__(16) unsigned short Ab[64 * 256];    // 32 KB bf16 h (A-layout, swizzled)
  __shared__ __align__(16) unsigned short Sb[64 * 256];    // 32 KB multi-use
  __shared__ __align__(16) float temb[4 * 32];
  __shared__ __align__(16) float part_s[64 * 8];
  __shared__ __align__(16) float uf_s[64], vf_s[64], zok_s[64];
  __shared__ int sv_s[64];

  // Sb overlays: f32 proj scratch (first 16 KB); Ab96 (second 16 KB)
  float* Sbf   = (float*)Sb;
  float* cams  = Sbf;           // 512 f
  float* sc_s  = Sbf + 512;     // 512 f
  float* us_s  = Sbf + 1024;
  float* vs_s  = Sbf + 1536;
  float* zs_s  = Sbf + 2048;
  float* xyz_s = Sbf + 2560;    // 48 f
  unsigned short* Ab96 = Sb + 8192;   // 64 rows x 128 us

  const int tid = threadIdx.x;
  const int pbase = blockIdx.x * PTS;
  const bf16x8* wsf = (const bf16x8*)ws;

  // ================= S0 =================
  if (tid < 32) {
    const float* P = c2w + tid * 16;
    float t0 = P[3], t1 = P[7], t2 = P[11];
    #pragma unroll
    for (int a = 0; a < 3; ++a) {
      float r0 = P[a], r1 = P[4 + a], r2 = P[8 + a];
      cams[tid * 16 + a * 4 + 0] = r0;
      cams[tid * 16 + a * 4 + 1] = r1;
      cams[tid * 16 + a * 4 + 2] = r2;
      cams[tid * 16 + a * 4 + 3] = -(r0 * t0 + r1 * t1 + r2 * t2);
    }
    const float* KK = intr + tid * 9;
    cams[tid * 16 + 12] = KK[0];
    cams[tid * 16 + 13] = KK[4];
    cams[tid * 16 + 14] = KK[2];
    cams[tid * 16 + 15] = KK[5];
  }
  if (tid < 128) {
    int ti = tid >> 5, e = tid & 31;
    int ta = time_ids[0], tb = time_ids[1], tc = time_ids[2], td = time_ids[3];
    int tmn = min(min(ta, tb), min(tc, td));
    int tmx = max(max(ta, tb), max(tc, td));
    tmx = max(tmx, tmn + 1);
    float tn = (float)(time_ids[ti] - tmn) / (float)(tmx - tmn);
    float ph = tn * expf((8.0f / 15.0f) * (float)(e & 15));
    temb[ti * 32 + e] = (e < 16) ? sinf(ph) : cosf(ph);
  }
  if (tid < PTS * 3) {
    int p = pbase + tid / 3;
    xyz_s[tid] = (p < M) ? xyz[p * 3 + tid % 3] : 0.0f;
  }
  __syncthreads();

  // ================= S1: project 16 pts x 32 cams =================
  #pragma unroll
  for (int pp = 0; pp < 2; ++pp) {
    int pt = (tid >> 5) + pp * 8, cam = tid & 31;
    float X = xyz_s[pt * 3], Y = xyz_s[pt * 3 + 1], Z = xyz_s[pt * 3 + 2];
    const float* cm = cams + cam * 16;
    float xc = cm[0] * X + cm[1] * Y + cm[2] * Z + cm[3];
    float yc = cm[4] * X + cm[5] * Y + cm[6] * Z + cm[7];
    float zc = cm[8] * X + cm[9] * Y + cm[10] * Z + cm[11];
    float wden = fmaxf(zc, 1e-6f);
    float u = (cm[12] * xc + cm[14] * zc) / wden;
    float v = (cm[13] * yc + cm[15] * zc) / wden;
    float Wimg = 2.0f * intr[2], Himg = 2.0f * intr[5];
    bool vis = (zc > 1e-4f) && (u >= 0.0f) && (u < Wimg) && (v >= 0.0f) && (v < Himg);
    sc_s[pt * 32 + cam] = vis ? 1.0f / (fmaxf(zc, 0.1f) + 1e-6f) : 0.0f;
    us_s[pt * 32 + cam] = u;
    vs_s[pt * 32 + cam] = v;
    zs_s[pt * 32 + cam] = zc;
  }
  __syncthreads();

  // ================= S2: stable top-4 =================
  if (tid < PTS) {
    float b0 = -1.f, b1 = -1.f, b2 = -1.f, b3 = -1.f;
    int i0 = 0, i1 = 0, i2 = 0, i3 = 0;
    for (int i = 0; i < 32; ++i) {
      float s = sc_s[tid * 32 + i];
      if (s > b0)      { b3 = b2; i3 = i2; b2 = b1; i2 = i1; b1 = b0; i1 = i0; b0 = s; i0 = i; }
      else if (s > b1) { b3 = b2; i3 = i2; b2 = b1; i2 = i1; b1 = s; i1 = i; }
      else if (s > b2) { b3 = b2; i3 = i2; b2 = s; i2 = i; }
      else if (s > b3) { b3 = s; i3 = i; }
    }
    float Wimg = 2.0f * intr[2], Himg = 2.0f * intr[5];
    float su = 64.0f / fmaxf(1.0f, Wimg);
    float sv = 64.0f / fmaxf(1.0f, Himg);
    int sel[4] = { i0, i1, i2, i3 };
    #pragma unroll
    for (int kk = 0; kk < 4; ++kk) {
      int r = tid * 4 + kk, i = sel[kk];
      sv_s[r] = i;
      uf_s[r] = us_s[tid * 32 + i] * su;
      vf_s[r] = vs_s[tid * 32 + i] * sv;
      zok_s[r] = (zs_s[tid * 32 + i] > 1e-4f) ? 1.0f : 0.0f;
    }
  }
  __syncthreads();

  // ================= S3: bilinear sample -> Ab96 =================
  #pragma unroll 1
  for (int rr = 0; rr < 2; ++rr) {
    int r = (tid >> 3) + rr * 32, cg = tid & 7;
    int view = sv_s[r];
    float uf = fminf(fmaxf(uf_s[r], -4.0f), 68.0f);
    float vf = fminf(fmaxf(vf_s[r], -4.0f), 68.0f);
    float x0f = floorf(uf), y0f = floorf(vf);
    float fx = uf - x0f, fy = vf - y0f;
    int x0 = (int)x0f, y0 = (int)y0f;
    float wgt[4] = { (1.0f - fx) * (1.0f - fy), fx * (1.0f - fy), (1.0f - fx) * fy, fx * fy };
    int xs[4] = { x0, x0 + 1, x0, x0 + 1 };
    int ys[4] = { y0, y0, y0 + 1, y0 + 1 };
    float acc[8] = { 0, 0, 0, 0, 0, 0, 0, 0 };
    #pragma unroll
    for (int c4 = 0; c4 < 4; ++c4) {
      int xi = xs[c4], yi = ys[c4];
      bool ok = (xi >= 0) && (xi < 64) && (yi >= 0) && (yi < 64);
      float wv = ok ? wgt[c4] : 0.0f;
      int xcl = min(max(xi, 0), 63), ycl = min(max(yi, 0), 63);
      const float* fp8 = feat + ((view * 64 + ycl) * 64 + xcl) * 64 + cg * 8;
      float4 f0 = *(const float4*)fp8;
      float4 f1 = *(const float4*)(fp8 + 4);
      acc[0] = fmaf(wv, f0.x, acc[0]); acc[1] = fmaf(wv, f0.y, acc[1]);
      acc[2] = fmaf(wv, f0.z, acc[2]); acc[3] = fmaf(wv, f0.w, acc[3]);
      acc[4] = fmaf(wv, f1.x, acc[4]); acc[5] = fmaf(wv, f1.y, acc[5]);
      acc[6] = fmaf(wv, f1.z, acc[6]); acc[7] = fmaf(wv, f1.w, acc[7]);
    }
    float zok = zok_s[r];
    bf16x8 pk;
    #pragma unroll
    for (int m = 0; m < 8; ++m) pk[m] = (short)f2bf(acc[m] * zok);
    int pslot = cg ^ (r & 7);
    *(bf16x8*)(Ab96 + r * 128 + pslot * 8) = pk;
  }
  // ================= S3b: pos32 -> Ab96 (8 cols/thread) =================
  {
    int r = tid & 63, cq = tid >> 6;
    int view = sv_s[r];
    int tix = view >> 3, vix = view & 7;
    float a[8] = { 0, 0, 0, 0, 0, 0, 0, 0 };
    #pragma unroll 4
    for (int e = 0; e < 32; ++e) {
      float av = temb[tix * 32 + e];
      float4 w0 = *(const float4*)(pos_w + e * 32 + cq * 8);
      float4 w1 = *(const float4*)(pos_w + e * 32 + cq * 8 + 4);
      a[0] = fmaf(av, w0.x, a[0]); a[1] = fmaf(av, w0.y, a[1]);
      a[2] = fmaf(av, w0.z, a[2]); a[3] = fmaf(av, w0.w, a[3]);
      a[4] = fmaf(av, w1.x, a[4]); a[5] = fmaf(av, w1.y, a[5]);
      a[6] = fmaf(av, w1.z, a[6]); a[7] = fmaf(av, w1.w, a[7]);
    }
    #pragma unroll 4
    for (int e = 0; e < 16; ++e) {
      float av = view_emb[vix * 16 + e];
      float4 w0 = *(const float4*)(pos_w + (32 + e) * 32 + cq * 8);
      float4 w1 = *(const float4*)(pos_w + (32 + e) * 32 + cq * 8 + 4);
      a[0] = fmaf(av, w0.x, a[0]); a[1] = fmaf(av, w0.y, a[1]);
      a[2] = fmaf(av, w0.z, a[2]); a[3] = fmaf(av, w0.w, a[3]);
      a[4] = fmaf(av, w1.x, a[4]); a[5] = fmaf(av, w1.y, a[5]);
      a[6] = fmaf(av, w1.z, a[6]); a[7] = fmaf(av, w1.w, a[7]);
    }
    #pragma unroll
    for (int j = 0; j < 8; ++j) {
      int col = 64 + cq * 8 + j;
      int pslot = (col >> 3) ^ (r & 7);
      Ab96[r * 128 + pslot * 8 + (col & 7)] = f2bf(a[j] + pos_b[cq * 8 + j]);
    }
  }
  __syncthreads();

  const int w = tid >> 6;
  const int l = tid & 63;
  const int g = l >> 4;
  const int lane15 = l & 15;
  const f32x4 vzero = { 0.f, 0.f, 0.f, 0.f };

  auto abIdx = [&](int row, int col) {
    return row * 256 + (((col >> 3) ^ (row & 7)) << 3) + (col & 7);
  };
  auto stSbB = [&](int row, int col, float v) {
    Sb[row * 256 + (((col >> 3) ^ (row & 7)) << 3) + (col & 7)] = f2bf(v);
  };

  // bias + bf16-residual(Ab) + LN; no register state across barriers.
  auto ln_apply = [&](f32x4 (&ac)[NRT][4], const float* bias, const float* lns,
                      const float* lnb) {
    #pragma unroll
    for (int rt = 0; rt < NRT; ++rt) {
      float sm[4] = { 0, 0, 0, 0 }, sq[4] = { 0, 0, 0, 0 };
      #pragma unroll
      for (int i = 0; i < 4; ++i) {
        int col = (w * 4 + i) * 16 + lane15;
        float bb = bias[col];
        #pragma unroll
        for (int reg = 0; reg < 4; ++reg) {
          int idx = abIdx(rt * 16 + g * 4 + reg, col);
          float x = ac[rt][i][reg] + bb + bf2f(Ab[idx]);
          Ab[idx] = f2bf(x);
          sm[reg] += x;
          sq[reg] += x * x;
        }
      }
      #pragma unroll
      for (int reg = 0; reg < 4; ++reg) {
        float s1 = sm[reg], s2 = sq[reg];
        s1 += __shfl_xor(s1, 1, 16); s1 += __shfl_xor(s1, 2, 16);
        s1 += __shfl_xor(s1, 4, 16); s1 += __shfl_xor(s1, 8, 16);
        s2 += __shfl_xor(s2, 1, 16); s2 += __shfl_xor(s2, 2, 16);
        s2 += __shfl_xor(s2, 4, 16); s2 += __shfl_xor(s2, 8, 16);
        if (lane15 == 0) {
          int row = rt * 16 + g * 4 + reg;
          part_s[row * 8 + w * 2] = s1;
          part_s[row * 8 + w * 2 + 1] = s2;
        }
      }
    }
    __syncthreads();
    #pragma unroll
    for (int rt = 0; rt < NRT; ++rt)
      #pragma unroll
      for (int reg = 0; reg < 4; ++reg) {
        int row = rt * 16 + g * 4 + reg;
        float sm = part_s[row * 8 + 0] + part_s[row * 8 + 2] +
                   part_s[row * 8 + 4] + part_s[row * 8 + 6];
        float sq = part_s[row * 8 + 1] + part_s[row * 8 + 3] +
                   part_s[row * 8 + 5] + part_s[row * 8 + 7];
        float mu = sm * (1.0f / 256.0f);
        float var = sq * (1.0f / 256.0f) - mu * mu;
        float rstd = rsqrtf(var + 1e-5f);
        #pragma unroll
        for (int i = 0; i < 4; ++i) {
          int col = (w * 4 + i) * 16 + lane15;
          int idx = abIdx(row, col);
          float x = bf2f(Ab[idx]);
          Ab[idx] = f2bf((x - mu) * rstd * lns[col] + lnb[col]);
        }
      }
    __syncthreads();
  };

  // rotation-pipelined pass over K (8 stages), 4 row-tiles x 2 B columns.
  // All macro-internal names carry a trailing underscore to avoid capture.
#define PASS2(ACC, ABUF, BOFF0, BOFF1) do { \
    bf16x8 pA0_ = ldAfrag(ABUF, 256, 0, 0, l); \
    bf16x8 pA1_ = ldAfrag(ABUF, 256, 1, 0, l); \
    bf16x8 pA2_ = ldAfrag(ABUF, 256, 2, 0, l); \
    bf16x8 pA3_ = ldAfrag(ABUF, 256, 3, 0, l); \
    bf16x8 pB0_ = wsf[(BOFF0) + l]; \
    bf16x8 pB1_ = wsf[(BOFF1) + l]; \
    _Pragma("unroll 1") \
    for (int s_ = 0; s_ < 7; ++s_) { \
      int sn_ = s_ + 1; \
      bf16x8 nA0_ = ldAfrag(ABUF, 256, 0, sn_, l); \
      bf16x8 nA1_ = ldAfrag(ABUF, 256, 1, sn_, l); \
      bf16x8 nA2_ = ldAfrag(ABUF, 256, 2, sn_, l); \
      bf16x8 nA3_ = ldAfrag(ABUF, 256, 3, sn_, l); \
      bf16x8 nB0_ = wsf[(BOFF0) + sn_ * 64 + l]; \
      bf16x8 nB1_ = wsf[(BOFF1) + sn_ * 64 + l]; \
      ACC[0][0] = MFMA16(pA0_, pB0_, ACC[0][0]); ACC[1][0] = MFMA16(pA1_, pB0_, ACC[1][0]); \
      ACC[2][0] = MFMA16(pA2_, pB0_, ACC[2][0]); ACC[3][0] = MFMA16(pA3_, pB0_, ACC[3][0]); \
      ACC[0][1] = MFMA16(pA0_, pB1_, ACC[0][1]); ACC[1][1] = MFMA16(pA1_, pB1_, ACC[1][1]); \
      ACC[2][1] = MFMA16(pA2_, pB1_, ACC[2][1]); ACC[3][1] = MFMA16(pA3_, pB1_, ACC[3][1]); \
      pA0_ = nA0_; pA1_ = nA1_; pA2_ = nA2_; pA3_ = nA3_; pB0_ = nB0_; pB1_ = nB1_; \
    } \
    ACC[0][0] = MFMA16(pA0_, pB0_, ACC[0][0]); ACC[1][0] = MFMA16(pA1_, pB0_, ACC[1][0]); \
    ACC[2][0] = MFMA16(pA2_, pB0_, ACC[2][0]); ACC[3][0] = MFMA16(pA3_, pB0_, ACC[3][0]); \
    ACC[0][1] = MFMA16(pA0_, pB1_, ACC[0][1]); ACC[1][1] = MFMA16(pA1_, pB1_, ACC[1][1]); \
    ACC[2][1] = MFMA16(pA2_, pB1_, ACC[2][1]); ACC[3][1] = MFMA16(pA3_, pB1_, ACC[3][1]); \
  } while (0)

  // ================= S4: h0 = [sampled|pos32] @ fp_w + fp_b =================
  {
    f32x4 accF[NRT][4];
    #pragma unroll
    for (int rt = 0; rt < NRT; ++rt)
      #pragma unroll
      for (int i = 0; i < 4; ++i) accF[rt][i] = vzero;
    #pragma unroll 1
    for (int s = 0; s < 3; ++s) {
      bf16x8 af[NRT];
      #pragma unroll
      for (int rt = 0; rt < NRT; ++rt) af[rt] = ldAfrag(Ab96, 128, rt, s, l);
      #pragma unroll
      for (int i = 0; i < 4; ++i) {
        bf16x8 b = wsf[FRAG_FP + ((w * 4 + i) * 3 + s) * 64 + l];
        #pragma unroll
        for (int rt = 0; rt < NRT; ++rt) accF[rt][i] = MFMA16(af[rt], b, accF[rt][i]);
      }
    }
    #pragma unroll
    for (int rt = 0; rt < NRT; ++rt)
      #pragma unroll
      for (int i = 0; i < 4; ++i) {
        int col = (w * 4 + i) * 16 + lane15;
        float bb = fp_b[col];
        #pragma unroll
        for (int reg = 0; reg < 4; ++reg)
          Ab[abIdx(rt * 16 + g * 4 + reg, col)] = f2bf(accF[rt][i][reg] + bb);
      }
  }
  __syncthreads();

  // ================= S5: 2 transformer layers =================
  for (int lyr = 0; lyr < 2; ++lyr) {
    const int QKVo = (lyr == 0) ? FRAG_QKV0 : FRAG_QKV1;
    const int AOo  = (lyr == 0) ? FRAG_AO0  : FRAG_AO1;
    const int FF1o = (lyr == 0) ? FRAG_FF1_0 : FRAG_FF1_1;
    const int FF2o = (lyr == 0) ? FRAG_FF2_0 : FRAG_FF2_1;
    const float* qbl  = qkv_b + lyr * 768;
    const float* aobl = ao_b + lyr * 256;
    const float* l1s  = ln1_s + lyr * 256;
    const float* l1b  = ln1_b + lyr * 256;
    const float* f1bl = ff1_b + lyr * 512;
    const float* f2bl = ff2_b + lyr * 256;
    const float* l2s  = ln2_s + lyr * 256;
    const float* l2b  = ln2_b + lyr * 256;

    // ---- qkv + attention: per head, 3 split passes (q, k, v) ----
    for (int hh = 0; hh < 2; ++hh) {
      const int hc0 = (2 * w + hh) * 2, hc1 = hc0 + 1;
      f32x4 aq[NRT][2], ak[NRT][2], av[NRT][2];
      #pragma unroll
      for (int rt = 0; rt < NRT; ++rt)
        #pragma unroll
        for (int c = 0; c < 2; ++c) { aq[rt][c] = vzero; ak[rt][c] = vzero; av[rt][c] = vzero; }
      PASS2(aq, Ab, QKVo + (hc0 * 8) * 64, QKVo + (hc1 * 8) * 64);
      PASS2(ak, Ab, QKVo + ((16 + hc0) * 8) * 64, QKVo + ((16 + hc1) * 8) * 64);
      PASS2(av, Ab, QKVo + ((32 + hc0) * 8) * 64, QKVo + ((32 + hc1) * 8) * 64);

      #pragma unroll
      for (int c = 0; c < 2; ++c) {
        int cb = (2 * w + hh) * 32 + c * 16 + lane15;
        float bq = qbl[cb], bk = qbl[256 + cb], bv = qbl[512 + cb];
        #pragma unroll
        for (int rt = 0; rt < NRT; ++rt)
          #pragma unroll
          for (int reg = 0; reg < 4; ++reg) {
            aq[rt][c][reg] += bq;
            ak[rt][c][reg] += bk;
            av[rt][c][reg] += bv;
          }
      }
      #pragma unroll
      for (int rt = 0; rt < NRT; ++rt) {
        float sc[4][4];
        #pragma unroll
        for (int r1 = 0; r1 < 4; ++r1)
          #pragma unroll
          for (int r2 = 0; r2 < 4; ++r2) {
            float p = aq[rt][0][r1] * ak[rt][0][r2] + aq[rt][1][r1] * ak[rt][1][r2];
            p += __shfl_xor(p, 1, 16); p += __shfl_xor(p, 2, 16);
            p += __shfl_xor(p, 4, 16); p += __shfl_xor(p, 8, 16);
            sc[r1][r2] = p * 0.17677669529663689f;  // 1/sqrt(32)
          }
        #pragma unroll
        for (int r1 = 0; r1 < 4; ++r1) {
          float mx = fmaxf(fmaxf(sc[r1][0], sc[r1][1]), fmaxf(sc[r1][2], sc[r1][3]));
          float e0 = __expf(sc[r1][0] - mx), e1 = __expf(sc[r1][1] - mx);
          float e2 = __expf(sc[r1][2] - mx), e3 = __expf(sc[r1][3] - mx);
          float inv = 1.0f / (e0 + e1 + e2 + e3);
          int row = rt * 16 + g * 4 + r1;
          #pragma unroll
          for (int c = 0; c < 2; ++c) {
            float o = (e0 * av[rt][c][0] + e1 * av[rt][c][1] +
                       e2 * av[rt][c][2] + e3 * av[rt][c][3]) * inv;
            stSbB(row, (2 * w + hh) * 32 + c * 16 + lane15, o);
          }
        }
      }
    }
    __syncthreads();

    // ---- ao GEMM (two 2-col passes) + residual + LN1 ----
    {
      f32x4 accA[NRT][4];
      #pragma unroll
      for (int rt = 0; rt < NRT; ++rt)
        #pragma unroll
        for (int i = 0; i < 4; ++i) accA[rt][i] = vzero;
      #pragma unroll 1
      for (int ig = 0; ig < 2; ++ig) {
        f32x4 accP[NRT][2];
        #pragma unroll
        for (int rt = 0; rt < NRT; ++rt) {
          accP[rt][0] = accA[rt][ig * 2];
          accP[rt][1] = accA[rt][ig * 2 + 1];
        }
        PASS2(accP, Sb, AOo + ((w * 4 + ig * 2) * 8) * 64, AOo + ((w * 4 + ig * 2 + 1) * 8) * 64);
        #pragma unroll
        for (int rt = 0; rt < NRT; ++rt) {
          accA[rt][ig * 2] = accP[rt][0];
          accA[rt][ig * 2 + 1] = accP[rt][1];
        }
      }
      ln_apply(accA, aobl, l1s, l1b);
    }

    // ---- FF block: ff1 in 2 col-groups; ff2 accumulates acc2 ----
    {
      f32x4 acc2[NRT][4];
      #pragma unroll
      for (int rt = 0; rt < NRT; ++rt)
        #pragma unroll
        for (int i = 0; i < 4; ++i) acc2[rt][i] = vzero;
      #pragma unroll 1
      for (int half = 0; half < 2; ++half) {
        #pragma unroll 1
        for (int ig = 0; ig < 2; ++ig) {
          f32x4 accH[NRT][2];
          #pragma unroll
          for (int rt = 0; rt < NRT; ++rt) { accH[rt][0] = vzero; accH[rt][1] = vzero; }
          const int fc0 = half * 16 + w * 4 + ig * 2;
          PASS2(accH, Ab, FF1o + (fc0 * 8) * 64, FF1o + ((fc0 + 1) * 8) * 64);
          #pragma unroll
          for (int rt = 0; rt < NRT; ++rt)
            #pragma unroll
            for (int j = 0; j < 2; ++j) {
              int lcol = (w * 4 + ig * 2 + j) * 16 + lane15;
              float bb = f1bl[half * 256 + lcol];
              #pragma unroll
              for (int reg = 0; reg < 4; ++reg) {
                int row = rt * 16 + g * 4 + reg;
                stSbB(row, lcol, fmaxf(accH[rt][j][reg] + bb, 0.0f));
              }
            }
        }
        __syncthreads();
        #pragma unroll 1
        for (int ig = 0; ig < 2; ++ig) {
          f32x4 accP[NRT][2];
          #pragma unroll
          for (int rt = 0; rt < NRT; ++rt) {
            accP[rt][0] = acc2[rt][ig * 2];
            accP[rt][1] = acc2[rt][ig * 2 + 1];
          }
          const int bo0 = FF2o + ((w * 4 + ig * 2) * 16 + half * 8) * 64;
          const int bo1 = FF2o + ((w * 4 + ig * 2 + 1) * 16 + half * 8) * 64;
          PASS2(accP, Sb, bo0, bo1);
          #pragma unroll
          for (int rt = 0; rt < NRT; ++rt) {
            acc2[rt][ig * 2] = accP[rt][0];
            acc2[rt][ig * 2 + 1] = accP[rt][1];
          }
        }
        __syncthreads();
      }
      ln_apply(acc2, f2bl, l2s, l2b);
    }
  }

  // ================= S6: mean over views + MFMA out head =================
  {
    #pragma unroll 1
    for (int pp = 0; pp < 2; ++pp) {
      const int ptg = (tid >> 5) + pp * 8;
      const int lid = tid & 31;
      const int rb = ptg * 4;
      float gg[8];
      #pragma unroll
      for (int m = 0; m < 8; ++m) gg[m] = 0.0f;
      #pragma unroll
      for (int r4 = 0; r4 < 4; ++r4) {
        int row = rb + r4;
        int slot = lid ^ (row & 7);
        bf16x8 hv = *(const bf16x8*)(Ab + row * 256 + slot * 8);
        #pragma unroll
        for (int m = 0; m < 8; ++m) gg[m] += bf2f((unsigned short)hv[m]);
      }
      bf16x8 pk;
      #pragma unroll
      for (int m = 0; m < 8; ++m) pk[m] = (short)f2bf(gg[m] * 0.25f);
      int slot = lid ^ (ptg & 7);
      *(bf16x8*)(Sb + ptg * 256 + slot * 8) = pk;
    }
    __syncthreads();
    f32x4 accO = vzero;
    #pragma unroll 1
    for (int s = 0; s < 8; ++s) {
      bf16x8 a = ldAfrag(Sb, 256, 0, s, l);
      bf16x8 b = wsf[FRAG_OUT + (w * 8 + s) * 64 + l];
      accO = MFMA16(a, b, accO);
    }
    int col = w * 16 + lane15;
    float ob = out_b[col];
    #pragma unroll
    for (int reg = 0; reg < 4; ++reg) {
      int row = g * 4 + reg;   // 0..15 = point within WG
      int p = pbase + row;
      if (p < M) outp[p * 64 + col] = accO[reg] + ob;
    }
  }
}

extern "C" void kernel_launch(void* const* d_in, const int* in_sizes, int n_in,
                              void* d_out, int out_size, void* d_ws, size_t ws_size,
                              hipStream_t stream) {
  (void)n_in; (void)out_size;
  const float* xyz   = (const float*)d_in[0];
  const float* feat  = (const float*)d_in[1];
  const float* c2w   = (const float*)d_in[2];
  const float* intr  = (const float*)d_in[3];
  const int*   tids  = (const int*)d_in[4];
  const float* vemb  = (const float*)d_in[5];
  const float* pos_w = (const float*)d_in[6];
  const float* pos_b = (const float*)d_in[7];
  const float* fp_w  = (const float*)d_in[8];
  const float* fp_b  = (const float*)d_in[9];
  const float* qkv_w = (const float*)d_in[10];
  const float* qkv_b = (const float*)d_in[11];
  const float* ao_w  = (const float*)d_in[12];
  const float* ao_b  = (const float*)d_in[13];
  const float* ln1s  = (const float*)d_in[14];
  const float* ln1b  = (const float*)d_in[15];
  const float* ff1_w = (const float*)d_in[16];
  const float* ff1_b = (const float*)d_in[17];
  const float* ff2_w = (const float*)d_in[18];
  const float* ff2_b = (const float*)d_in[19];
  const float* ln2s  = (const float*)d_in[20];
  const float* ln2b  = (const float*)d_in[21];
  const float* out_w = (const float*)d_in[22];
  const float* out_b = (const float*)d_in[23];
  float* outp = (float*)d_out;

  if (ws_size < (size_t)FRAG_TOTAL * 16) return;

  unsigned short* wsp = (unsigned short*)d_ws;
  hipLaunchKernelGGL(prepack_kernel, dim3((FRAG_TOTAL + 255) / 256), dim3(256), 0, stream,
                     fp_w, qkv_w, ao_w, ff1_w, ff2_w, out_w, wsp);

  int M = in_sizes[0] / 3;
  int nblk = (M + PTS - 1) / PTS;
  hipLaunchKernelGGL(mvpa_kernel, dim3(nblk), dim3(256), 0, stream,
                     xyz, feat, c2w, intr, tids, vemb, pos_w, pos_b, fp_b, qkv_b,
                     ao_b, ln1s, ln1b, ff1_b, ff2_b, ln2s, ln2b, out_b,
                     wsp, outp, M);
}

// Round 15
// 1193.243 us; speedup vs baseline: 1.2742x; 1.2742x over previous
//
#include <hip/hip_runtime.h>
#include <math.h>

// ============================================================================
// MultiViewPointAggregator — MFMA bf16, round 15.
// = r12 (best, 1.19 ms: PTS=8, rotation-pipelined K-loops, MFMA out-head)
// + s_setprio(1) around the MFMA rotation loops (T5; independent WGs/CU give
// the scheduler role diversity to arbitrate).
// ============================================================================

typedef __attribute__((ext_vector_type(8))) short bf16x8;
typedef __attribute__((ext_vector_type(4))) float f32x4;

#define MFMA16(a, b, c) __builtin_amdgcn_mfma_f32_16x16x32_bf16((a), (b), (c), 0, 0, 0)

__device__ __forceinline__ unsigned short f2bf(float f) {
  unsigned u = __float_as_uint(f);
  return (unsigned short)((u + 0x7fffu + ((u >> 16) & 1u)) >> 16);  // RNE
}
__device__ __forceinline__ float bf2f(unsigned short u) {
  return __uint_as_float((unsigned)u << 16);
}

__device__ __forceinline__ bf16x8 ldAfrag(const unsigned short* base, int stride_us,
                                          int rt, int s, int l) {
  int row = rt * 16 + (l & 15);
  int slot = ((s << 2) + (l >> 4)) ^ (row & 7);
  return *(const bf16x8*)(base + row * stride_us + slot * 8);
}

// ---- ws segment offsets, in 64-lane*8-elem fragments (16B each) ----
#define FRAG_FP    0
#define FRAG_QKV0  3072
#define FRAG_QKV1  27648
#define FRAG_AO0   52224
#define FRAG_AO1   60416
#define FRAG_FF1_0 68608
#define FRAG_FF1_1 84992
#define FRAG_FF2_0 101376
#define FRAG_FF2_1 117760
#define FRAG_OUT   134144
#define FRAG_TOTAL 136192   // * 16B = 2179072 bytes

__global__ __launch_bounds__(256, 2)
void prepack_kernel(const float* __restrict__ fp_w, const float* __restrict__ qkv_w,
                    const float* __restrict__ ao_w, const float* __restrict__ ff1_w,
                    const float* __restrict__ ff2_w, const float* __restrict__ out_w,
                    unsigned short* __restrict__ ws) {
  int f = blockIdx.x * 256 + threadIdx.x;
  if (f >= FRAG_TOTAL) return;
  const float* W;
  int N, S, base;
  if (f < FRAG_QKV0)       { W = fp_w;            N = 256; S = 3;  base = FRAG_FP; }
  else if (f < FRAG_QKV1)  { W = qkv_w;           N = 768; S = 8;  base = FRAG_QKV0; }
  else if (f < FRAG_AO0)   { W = qkv_w + 196608;  N = 768; S = 8;  base = FRAG_QKV1; }
  else if (f < FRAG_AO1)   { W = ao_w;            N = 256; S = 8;  base = FRAG_AO0; }
  else if (f < FRAG_FF1_0) { W = ao_w + 65536;    N = 256; S = 8;  base = FRAG_AO1; }
  else if (f < FRAG_FF1_1) { W = ff1_w;           N = 512; S = 8;  base = FRAG_FF1_0; }
  else if (f < FRAG_FF2_0) { W = ff1_w + 131072;  N = 512; S = 8;  base = FRAG_FF1_1; }
  else if (f < FRAG_FF2_1) { W = ff2_w;           N = 256; S = 16; base = FRAG_FF2_0; }
  else if (f < FRAG_OUT)   { W = ff2_w + 131072;  N = 256; S = 16; base = FRAG_FF2_1; }
  else                     { W = out_w;           N = 64;  S = 8;  base = FRAG_OUT; }
  int r = f - base;
  int l = r & 63;
  int cs = r >> 6;
  int s = cs % S;
  int ct = cs / S;
  int k0 = s * 32 + (l >> 4) * 8;
  int col = ct * 16 + (l & 15);
  bf16x8 pk;
  #pragma unroll
  for (int j = 0; j < 8; ++j)
    pk[j] = (short)f2bf(W[(size_t)(k0 + j) * N + col]);
  *(bf16x8*)(ws + (size_t)f * 8) = pk;
}

#define PTS 8

__global__ __launch_bounds__(256, 2)
void mvpa_kernel(
    const float* __restrict__ xyz, const float* __restrict__ feat,
    const float* __restrict__ c2w, const float* __restrict__ intr,
    const int* __restrict__ time_ids, const float* __restrict__ view_emb,
    const float* __restrict__ pos_w, const float* __restrict__ pos_b,
    const float* __restrict__ fp_b, const float* __restrict__ qkv_b,
    const float* __restrict__ ao_b, const float* __restrict__ ln1_s,
    const float* __restrict__ ln1_b, const float* __restrict__ ff1_b,
    const float* __restrict__ ff2_b, const float* __restrict__ ln2_s,
    const float* __restrict__ ln2_b, const float* __restrict__ out_b,
    const unsigned short* __restrict__ ws, float* __restrict__ outp, int M)
{
  __shared__ __align__(16) unsigned short Ab[32 * 256];    // 16 KB bf16 h (A-layout, swizzled)
  __shared__ __align__(16) unsigned short Sb[32 * 256];    // 16 KB multi-use
  __shared__ __align__(16) float temb[4 * 32];
  __shared__ __align__(16) float part_s[32 * 8];
  __shared__ __align__(16) float uf_s[32], vf_s[32], zok_s[32];
  __shared__ int sv_s[32];

  float* Sbf   = (float*)Sb;
  float* cams  = Sbf;
  float* sc_s  = Sbf + 512;
  float* us_s  = Sbf + 768;
  float* vs_s  = Sbf + 1024;
  float* zs_s  = Sbf + 1280;
  float* xyz_s = Sbf + 1536;
  unsigned short* Ab96 = Sb + 4096;

  const int tid = threadIdx.x;
  const int pbase = blockIdx.x * PTS;
  const bf16x8* wsf = (const bf16x8*)ws;

  // ================= S0 =================
  if (tid < 32) {
    const float* P = c2w + tid * 16;
    float t0 = P[3], t1 = P[7], t2 = P[11];
    #pragma unroll
    for (int a = 0; a < 3; ++a) {
      float r0 = P[a], r1 = P[4 + a], r2 = P[8 + a];
      cams[tid * 16 + a * 4 + 0] = r0;
      cams[tid * 16 + a * 4 + 1] = r1;
      cams[tid * 16 + a * 4 + 2] = r2;
      cams[tid * 16 + a * 4 + 3] = -(r0 * t0 + r1 * t1 + r2 * t2);
    }
    const float* KK = intr + tid * 9;
    cams[tid * 16 + 12] = KK[0];
    cams[tid * 16 + 13] = KK[4];
    cams[tid * 16 + 14] = KK[2];
    cams[tid * 16 + 15] = KK[5];
  }
  if (tid < 128) {
    int ti = tid >> 5, e = tid & 31;
    int ta = time_ids[0], tb = time_ids[1], tc = time_ids[2], td = time_ids[3];
    int tmn = min(min(ta, tb), min(tc, td));
    int tmx = max(max(ta, tb), max(tc, td));
    tmx = max(tmx, tmn + 1);
    float tn = (float)(time_ids[ti] - tmn) / (float)(tmx - tmn);
    float ph = tn * expf((8.0f / 15.0f) * (float)(e & 15));
    temb[ti * 32 + e] = (e < 16) ? sinf(ph) : cosf(ph);
  }
  if (tid < PTS * 3) {
    int p = pbase + tid / 3;
    xyz_s[tid] = (p < M) ? xyz[p * 3 + tid % 3] : 0.0f;
  }
  __syncthreads();

  // ================= S1: project =================
  {
    int pt = tid >> 5, cam = tid & 31;
    float X = xyz_s[pt * 3], Y = xyz_s[pt * 3 + 1], Z = xyz_s[pt * 3 + 2];
    const float* cm = cams + cam * 16;
    float xc = cm[0] * X + cm[1] * Y + cm[2] * Z + cm[3];
    float yc = cm[4] * X + cm[5] * Y + cm[6] * Z + cm[7];
    float zc = cm[8] * X + cm[9] * Y + cm[10] * Z + cm[11];
    float wden = fmaxf(zc, 1e-6f);
    float u = (cm[12] * xc + cm[14] * zc) / wden;
    float v = (cm[13] * yc + cm[15] * zc) / wden;
    float Wimg = 2.0f * intr[2], Himg = 2.0f * intr[5];
    bool vis = (zc > 1e-4f) && (u >= 0.0f) && (u < Wimg) && (v >= 0.0f) && (v < Himg);
    sc_s[pt * 32 + cam] = vis ? 1.0f / (fmaxf(zc, 0.1f) + 1e-6f) : 0.0f;
    us_s[pt * 32 + cam] = u;
    vs_s[pt * 32 + cam] = v;
    zs_s[pt * 32 + cam] = zc;
  }
  __syncthreads();

  // ================= S2: stable top-4 =================
  if (tid < PTS) {
    float b0 = -1.f, b1 = -1.f, b2 = -1.f, b3 = -1.f;
    int i0 = 0, i1 = 0, i2 = 0, i3 = 0;
    for (int i = 0; i < 32; ++i) {
      float s = sc_s[tid * 32 + i];
      if (s > b0)      { b3 = b2; i3 = i2; b2 = b1; i2 = i1; b1 = b0; i1 = i0; b0 = s; i0 = i; }
      else if (s > b1) { b3 = b2; i3 = i2; b2 = b1; i2 = i1; b1 = s; i1 = i; }
      else if (s > b2) { b3 = b2; i3 = i2; b2 = s; i2 = i; }
      else if (s > b3) { b3 = s; i3 = i; }
    }
    float Wimg = 2.0f * intr[2], Himg = 2.0f * intr[5];
    float su = 64.0f / fmaxf(1.0f, Wimg);
    float sv = 64.0f / fmaxf(1.0f, Himg);
    int sel[4] = { i0, i1, i2, i3 };
    #pragma unroll
    for (int kk = 0; kk < 4; ++kk) {
      int r = tid * 4 + kk, i = sel[kk];
      sv_s[r] = i;
      uf_s[r] = us_s[tid * 32 + i] * su;
      vf_s[r] = vs_s[tid * 32 + i] * sv;
      zok_s[r] = (zs_s[tid * 32 + i] > 1e-4f) ? 1.0f : 0.0f;
    }
  }
  __syncthreads();

  // ================= S3: bilinear sample -> Ab96 =================
  {
    int r = tid >> 3, cg = tid & 7;
    int view = sv_s[r];
    float uf = fminf(fmaxf(uf_s[r], -4.0f), 68.0f);
    float vf = fminf(fmaxf(vf_s[r], -4.0f), 68.0f);
    float x0f = floorf(uf), y0f = floorf(vf);
    float fx = uf - x0f, fy = vf - y0f;
    int x0 = (int)x0f, y0 = (int)y0f;
    float wgt[4] = { (1.0f - fx) * (1.0f - fy), fx * (1.0f - fy), (1.0f - fx) * fy, fx * fy };
    int xs[4] = { x0, x0 + 1, x0, x0 + 1 };
    int ys[4] = { y0, y0, y0 + 1, y0 + 1 };
    float acc[8] = { 0, 0, 0, 0, 0, 0, 0, 0 };
    #pragma unroll
    for (int c4 = 0; c4 < 4; ++c4) {
      int xi = xs[c4], yi = ys[c4];
      bool ok = (xi >= 0) && (xi < 64) && (yi >= 0) && (yi < 64);
      float wv = ok ? wgt[c4] : 0.0f;
      int xcl = min(max(xi, 0), 63), ycl = min(max(yi, 0), 63);
      const float* fp8 = feat + ((view * 64 + ycl) * 64 + xcl) * 64 + cg * 8;
      float4 f0 = *(const float4*)fp8;
      float4 f1 = *(const float4*)(fp8 + 4);
      acc[0] = fmaf(wv, f0.x, acc[0]); acc[1] = fmaf(wv, f0.y, acc[1]);
      acc[2] = fmaf(wv, f0.z, acc[2]); acc[3] = fmaf(wv, f0.w, acc[3]);
      acc[4] = fmaf(wv, f1.x, acc[4]); acc[5] = fmaf(wv, f1.y, acc[5]);
      acc[6] = fmaf(wv, f1.z, acc[6]); acc[7] = fmaf(wv, f1.w, acc[7]);
    }
    float zok = zok_s[r];
    bf16x8 pk;
    #pragma unroll
    for (int m = 0; m < 8; ++m) pk[m] = (short)f2bf(acc[m] * zok);
    int pslot = cg ^ (r & 7);
    *(bf16x8*)(Ab96 + r * 128 + pslot * 8) = pk;
  }
  // ================= S3b: pos32 -> Ab96 =================
  {
    int r = tid & 31, cq = tid >> 5;
    int view = sv_s[r];
    int tix = view >> 3, vix = view & 7;
    float a0 = 0, a1 = 0, a2 = 0, a3 = 0;
    #pragma unroll 4
    for (int e = 0; e < 32; ++e) {
      float av = temb[tix * 32 + e];
      float4 wr = *(const float4*)(pos_w + e * 32 + cq * 4);
      a0 = fmaf(av, wr.x, a0); a1 = fmaf(av, wr.y, a1);
      a2 = fmaf(av, wr.z, a2); a3 = fmaf(av, wr.w, a3);
    }
    #pragma unroll 4
    for (int e = 0; e < 16; ++e) {
      float av = view_emb[vix * 16 + e];
      float4 wr = *(const float4*)(pos_w + (32 + e) * 32 + cq * 4);
      a0 = fmaf(av, wr.x, a0); a1 = fmaf(av, wr.y, a1);
      a2 = fmaf(av, wr.z, a2); a3 = fmaf(av, wr.w, a3);
    }
    float vals[4] = { a0 + pos_b[cq * 4 + 0], a1 + pos_b[cq * 4 + 1],
                      a2 + pos_b[cq * 4 + 2], a3 + pos_b[cq * 4 + 3] };
    #pragma unroll
    for (int j = 0; j < 4; ++j) {
      int col = 64 + cq * 4 + j;
      int pslot = (col >> 3) ^ (r & 7);
      Ab96[r * 128 + pslot * 8 + (col & 7)] = f2bf(vals[j]);
    }
  }
  __syncthreads();

  const int w = tid >> 6;
  const int l = tid & 63;
  const int g = l >> 4;
  const int lane15 = l & 15;
  const f32x4 vzero = { 0.f, 0.f, 0.f, 0.f };

  auto abIdx = [&](int row, int col) {
    return row * 256 + (((col >> 3) ^ (row & 7)) << 3) + (col & 7);
  };
  auto stSbB = [&](int row, int col, float v) {
    Sb[row * 256 + (((col >> 3) ^ (row & 7)) << 3) + (col & 7)] = f2bf(v);
  };

  // bias + bf16-residual(Ab) + LN; no register state across barriers.
  auto ln_apply = [&](f32x4 (&ac)[2][4], const float* bias, const float* lns,
                      const float* lnb) {
    #pragma unroll
    for (int rt = 0; rt < 2; ++rt) {
      float sm[4] = { 0, 0, 0, 0 }, sq[4] = { 0, 0, 0, 0 };
      #pragma unroll
      for (int i = 0; i < 4; ++i) {
        int col = (w * 4 + i) * 16 + lane15;
        float bb = bias[col];
        #pragma unroll
        for (int reg = 0; reg < 4; ++reg) {
          int idx = abIdx(rt * 16 + g * 4 + reg, col);
          float x = ac[rt][i][reg] + bb + bf2f(Ab[idx]);
          Ab[idx] = f2bf(x);
          sm[reg] += x;
          sq[reg] += x * x;
        }
      }
      #pragma unroll
      for (int reg = 0; reg < 4; ++reg) {
        float s1 = sm[reg], s2 = sq[reg];
        s1 += __shfl_xor(s1, 1, 16); s1 += __shfl_xor(s1, 2, 16);
        s1 += __shfl_xor(s1, 4, 16); s1 += __shfl_xor(s1, 8, 16);
        s2 += __shfl_xor(s2, 1, 16); s2 += __shfl_xor(s2, 2, 16);
        s2 += __shfl_xor(s2, 4, 16); s2 += __shfl_xor(s2, 8, 16);
        if (lane15 == 0) {
          int row = rt * 16 + g * 4 + reg;
          part_s[row * 8 + w * 2] = s1;
          part_s[row * 8 + w * 2 + 1] = s2;
        }
      }
    }
    __syncthreads();
    #pragma unroll
    for (int rt = 0; rt < 2; ++rt)
      #pragma unroll
      for (int reg = 0; reg < 4; ++reg) {
        int row = rt * 16 + g * 4 + reg;
        float sm = part_s[row * 8 + 0] + part_s[row * 8 + 2] +
                   part_s[row * 8 + 4] + part_s[row * 8 + 6];
        float sq = part_s[row * 8 + 1] + part_s[row * 8 + 3] +
                   part_s[row * 8 + 5] + part_s[row * 8 + 7];
        float mu = sm * (1.0f / 256.0f);
        float var = sq * (1.0f / 256.0f) - mu * mu;
        float rstd = rsqrtf(var + 1e-5f);
        #pragma unroll
        for (int i = 0; i < 4; ++i) {
          int col = (w * 4 + i) * 16 + lane15;
          int idx = abIdx(row, col);
          float x = bf2f(Ab[idx]);
          Ab[idx] = f2bf((x - mu) * rstd * lns[col] + lnb[col]);
        }
      }
    __syncthreads();
  };

  // ================= S4: h0 = [sampled|pos32] @ fp_w + fp_b =================
  {
    f32x4 accF[2][4] = { { vzero, vzero, vzero, vzero }, { vzero, vzero, vzero, vzero } };
    #pragma unroll 1
    for (int s = 0; s < 3; ++s) {
      bf16x8 a0 = ldAfrag(Ab96, 128, 0, s, l);
      bf16x8 a1 = ldAfrag(Ab96, 128, 1, s, l);
      #pragma unroll
      for (int i = 0; i < 4; ++i) {
        bf16x8 b = wsf[FRAG_FP + ((w * 4 + i) * 3 + s) * 64 + l];
        accF[0][i] = MFMA16(a0, b, accF[0][i]);
        accF[1][i] = MFMA16(a1, b, accF[1][i]);
      }
    }
    #pragma unroll
    for (int rt = 0; rt < 2; ++rt)
      #pragma unroll
      for (int i = 0; i < 4; ++i) {
        int col = (w * 4 + i) * 16 + lane15;
        float bb = fp_b[col];
        #pragma unroll
        for (int reg = 0; reg < 4; ++reg)
          Ab[abIdx(rt * 16 + g * 4 + reg, col)] = f2bf(accF[rt][i][reg] + bb);
      }
  }
  __syncthreads();

  // ================= S5: 2 transformer layers =================
  for (int lyr = 0; lyr < 2; ++lyr) {
    const int QKVo = (lyr == 0) ? FRAG_QKV0 : FRAG_QKV1;
    const int AOo  = (lyr == 0) ? FRAG_AO0  : FRAG_AO1;
    const int FF1o = (lyr == 0) ? FRAG_FF1_0 : FRAG_FF1_1;
    const int FF2o = (lyr == 0) ? FRAG_FF2_0 : FRAG_FF2_1;
    const float* qbl  = qkv_b + lyr * 768;
    const float* aobl = ao_b + lyr * 256;
    const float* l1s  = ln1_s + lyr * 256;
    const float* l1b  = ln1_b + lyr * 256;
    const float* f1bl = ff1_b + lyr * 512;
    const float* f2bl = ff2_b + lyr * 256;
    const float* l2s  = ln2_s + lyr * 256;
    const float* l2b  = ln2_b + lyr * 256;

    // ---- qkv GEMM + attention, per head; K-loop software-pipelined ----
    for (int hh = 0; hh < 2; ++hh) {
      f32x4 aq[2][2], ak[2][2], av[2][2];   // [rt][c]
      #pragma unroll
      for (int rt = 0; rt < 2; ++rt)
        #pragma unroll
        for (int c = 0; c < 2; ++c) { aq[rt][c] = vzero; ak[rt][c] = vzero; av[rt][c] = vzero; }
      const int hc0 = (2 * w + hh) * 2, hc1 = hc0 + 1;
      // prologue: stage s=0
      bf16x8 a0  = ldAfrag(Ab, 256, 0, 0, l);
      bf16x8 a1  = ldAfrag(Ab, 256, 1, 0, l);
      bf16x8 bq0 = wsf[QKVo + (hc0 * 8) * 64 + l];
      bf16x8 bq1 = wsf[QKVo + (hc1 * 8) * 64 + l];
      bf16x8 bk0 = wsf[QKVo + ((16 + hc0) * 8) * 64 + l];
      bf16x8 bk1 = wsf[QKVo + ((16 + hc1) * 8) * 64 + l];
      bf16x8 bv0 = wsf[QKVo + ((32 + hc0) * 8) * 64 + l];
      bf16x8 bv1 = wsf[QKVo + ((32 + hc1) * 8) * 64 + l];
      __builtin_amdgcn_s_setprio(1);
      #pragma unroll 1
      for (int s = 0; s < 7; ++s) {
        int sn = s + 1;
        // prefetch s+1
        bf16x8 na0  = ldAfrag(Ab, 256, 0, sn, l);
        bf16x8 na1  = ldAfrag(Ab, 256, 1, sn, l);
        bf16x8 nbq0 = wsf[QKVo + (hc0 * 8 + sn) * 64 + l];
        bf16x8 nbq1 = wsf[QKVo + (hc1 * 8 + sn) * 64 + l];
        bf16x8 nbk0 = wsf[QKVo + ((16 + hc0) * 8 + sn) * 64 + l];
        bf16x8 nbk1 = wsf[QKVo + ((16 + hc1) * 8 + sn) * 64 + l];
        bf16x8 nbv0 = wsf[QKVo + ((32 + hc0) * 8 + sn) * 64 + l];
        bf16x8 nbv1 = wsf[QKVo + ((32 + hc1) * 8 + sn) * 64 + l];
        // consume s
        aq[0][0] = MFMA16(a0, bq0, aq[0][0]); aq[1][0] = MFMA16(a1, bq0, aq[1][0]);
        aq[0][1] = MFMA16(a0, bq1, aq[0][1]); aq[1][1] = MFMA16(a1, bq1, aq[1][1]);
        ak[0][0] = MFMA16(a0, bk0, ak[0][0]); ak[1][0] = MFMA16(a1, bk0, ak[1][0]);
        ak[0][1] = MFMA16(a0, bk1, ak[0][1]); ak[1][1] = MFMA16(a1, bk1, ak[1][1]);
        av[0][0] = MFMA16(a0, bv0, av[0][0]); av[1][0] = MFMA16(a1, bv0, av[1][0]);
        av[0][1] = MFMA16(a0, bv1, av[0][1]); av[1][1] = MFMA16(a1, bv1, av[1][1]);
        // rotate
        a0 = na0; a1 = na1;
        bq0 = nbq0; bq1 = nbq1; bk0 = nbk0; bk1 = nbk1; bv0 = nbv0; bv1 = nbv1;
      }
      // epilogue s=7
      aq[0][0] = MFMA16(a0, bq0, aq[0][0]); aq[1][0] = MFMA16(a1, bq0, aq[1][0]);
      aq[0][1] = MFMA16(a0, bq1, aq[0][1]); aq[1][1] = MFMA16(a1, bq1, aq[1][1]);
      ak[0][0] = MFMA16(a0, bk0, ak[0][0]); ak[1][0] = MFMA16(a1, bk0, ak[1][0]);
      ak[0][1] = MFMA16(a0, bk1, ak[0][1]); ak[1][1] = MFMA16(a1, bk1, ak[1][1]);
      av[0][0] = MFMA16(a0, bv0, av[0][0]); av[1][0] = MFMA16(a1, bv0, av[1][0]);
      av[0][1] = MFMA16(a0, bv1, av[0][1]); av[1][1] = MFMA16(a1, bv1, av[1][1]);
      __builtin_amdgcn_s_setprio(0);

      #pragma unroll
      for (int c = 0; c < 2; ++c) {
        int cb = (2 * w + hh) * 32 + c * 16 + lane15;
        float bq = qbl[cb], bk = qbl[256 + cb], bv = qbl[512 + cb];
        #pragma unroll
        for (int rt = 0; rt < 2; ++rt)
          #pragma unroll
          for (int reg = 0; reg < 4; ++reg) {
            aq[rt][c][reg] += bq;
            ak[rt][c][reg] += bk;
            av[rt][c][reg] += bv;
          }
      }
      #pragma unroll
      for (int rt = 0; rt < 2; ++rt) {
        float sc[4][4];
        #pragma unroll
        for (int r1 = 0; r1 < 4; ++r1)
          #pragma unroll
          for (int r2 = 0; r2 < 4; ++r2) {
            float p = aq[rt][0][r1] * ak[rt][0][r2] + aq[rt][1][r1] * ak[rt][1][r2];
            p += __shfl_xor(p, 1, 16); p += __shfl_xor(p, 2, 16);
            p += __shfl_xor(p, 4, 16); p += __shfl_xor(p, 8, 16);
            sc[r1][r2] = p * 0.17677669529663689f;  // 1/sqrt(32)
          }
        #pragma unroll
        for (int r1 = 0; r1 < 4; ++r1) {
          float mx = fmaxf(fmaxf(sc[r1][0], sc[r1][1]), fmaxf(sc[r1][2], sc[r1][3]));
          float e0 = __expf(sc[r1][0] - mx), e1 = __expf(sc[r1][1] - mx);
          float e2 = __expf(sc[r1][2] - mx), e3 = __expf(sc[r1][3] - mx);
          float inv = 1.0f / (e0 + e1 + e2 + e3);
          int row = rt * 16 + g * 4 + r1;
          #pragma unroll
          for (int c = 0; c < 2; ++c) {
            float o = (e0 * av[rt][c][0] + e1 * av[rt][c][1] +
                       e2 * av[rt][c][2] + e3 * av[rt][c][3]) * inv;
            stSbB(row, (2 * w + hh) * 32 + c * 16 + lane15, o);
          }
        }
      }
    }
    __syncthreads();

    // ---- ao GEMM + residual + LN1 (pipelined) ----
    {
      f32x4 accA[2][4] = { { vzero, vzero, vzero, vzero }, { vzero, vzero, vzero, vzero } };
      bf16x8 a0 = ldAfrag(Sb, 256, 0, 0, l);
      bf16x8 a1 = ldAfrag(Sb, 256, 1, 0, l);
      bf16x8 b0 = wsf[AOo + ((w * 4 + 0) * 8) * 64 + l];
      bf16x8 b1 = wsf[AOo + ((w * 4 + 1) * 8) * 64 + l];
      bf16x8 b2 = wsf[AOo + ((w * 4 + 2) * 8) * 64 + l];
      bf16x8 b3 = wsf[AOo + ((w * 4 + 3) * 8) * 64 + l];
      __builtin_amdgcn_s_setprio(1);
      #pragma unroll 1
      for (int s = 0; s < 7; ++s) {
        int sn = s + 1;
        bf16x8 na0 = ldAfrag(Sb, 256, 0, sn, l);
        bf16x8 na1 = ldAfrag(Sb, 256, 1, sn, l);
        bf16x8 nb0 = wsf[AOo + ((w * 4 + 0) * 8 + sn) * 64 + l];
        bf16x8 nb1 = wsf[AOo + ((w * 4 + 1) * 8 + sn) * 64 + l];
        bf16x8 nb2 = wsf[AOo + ((w * 4 + 2) * 8 + sn) * 64 + l];
        bf16x8 nb3 = wsf[AOo + ((w * 4 + 3) * 8 + sn) * 64 + l];
        accA[0][0] = MFMA16(a0, b0, accA[0][0]); accA[1][0] = MFMA16(a1, b0, accA[1][0]);
        accA[0][1] = MFMA16(a0, b1, accA[0][1]); accA[1][1] = MFMA16(a1, b1, accA[1][1]);
        accA[0][2] = MFMA16(a0, b2, accA[0][2]); accA[1][2] = MFMA16(a1, b2, accA[1][2]);
        accA[0][3] = MFMA16(a0, b3, accA[0][3]); accA[1][3] = MFMA16(a1, b3, accA[1][3]);
        a0 = na0; a1 = na1; b0 = nb0; b1 = nb1; b2 = nb2; b3 = nb3;
      }
      accA[0][0] = MFMA16(a0, b0, accA[0][0]); accA[1][0] = MFMA16(a1, b0, accA[1][0]);
      accA[0][1] = MFMA16(a0, b1, accA[0][1]); accA[1][1] = MFMA16(a1, b1, accA[1][1]);
      accA[0][2] = MFMA16(a0, b2, accA[0][2]); accA[1][2] = MFMA16(a1, b2, accA[1][2]);
      accA[0][3] = MFMA16(a0, b3, accA[0][3]); accA[1][3] = MFMA16(a1, b3, accA[1][3]);
      __builtin_amdgcn_s_setprio(0);
      ln_apply(accA, aobl, l1s, l1b);
    }

    // ---- FF block (both inner K-loops pipelined) ----
    {
      f32x4 acc2[2][4] = { { vzero, vzero, vzero, vzero }, { vzero, vzero, vzero, vzero } };
      #pragma unroll 1
      for (int half = 0; half < 2; ++half) {
        {
          f32x4 accH[2][4] = { { vzero, vzero, vzero, vzero }, { vzero, vzero, vzero, vzero } };
          const int B0 = FF1o + (half * 16 + w * 4) * 8 * 64;
          bf16x8 a0 = ldAfrag(Ab, 256, 0, 0, l);
          bf16x8 a1 = ldAfrag(Ab, 256, 1, 0, l);
          bf16x8 b0 = wsf[B0 + (0 * 8) * 64 + l];
          bf16x8 b1 = wsf[B0 + (1 * 8) * 64 + l];
          bf16x8 b2 = wsf[B0 + (2 * 8) * 64 + l];
          bf16x8 b3 = wsf[B0 + (3 * 8) * 64 + l];
          __builtin_amdgcn_s_setprio(1);
          #pragma unroll 1
          for (int s = 0; s < 7; ++s) {
            int sn = s + 1;
            bf16x8 na0 = ldAfrag(Ab, 256, 0, sn, l);
            bf16x8 na1 = ldAfrag(Ab, 256, 1, sn, l);
            bf16x8 nb0 = wsf[B0 + (0 * 8 + sn) * 64 + l];
            bf16x8 nb1 = wsf[B0 + (1 * 8 + sn) * 64 + l];
            bf16x8 nb2 = wsf[B0 + (2 * 8 + sn) * 64 + l];
            bf16x8 nb3 = wsf[B0 + (3 * 8 + sn) * 64 + l];
            accH[0][0] = MFMA16(a0, b0, accH[0][0]); accH[1][0] = MFMA16(a1, b0, accH[1][0]);
            accH[0][1] = MFMA16(a0, b1, accH[0][1]); accH[1][1] = MFMA16(a1, b1, accH[1][1]);
            accH[0][2] = MFMA16(a0, b2, accH[0][2]); accH[1][2] = MFMA16(a1, b2, accH[1][2]);
            accH[0][3] = MFMA16(a0, b3, accH[0][3]); accH[1][3] = MFMA16(a1, b3, accH[1][3]);
            a0 = na0; a1 = na1; b0 = nb0; b1 = nb1; b2 = nb2; b3 = nb3;
          }
          accH[0][0] = MFMA16(a0, b0, accH[0][0]); accH[1][0] = MFMA16(a1, b0, accH[1][0]);
          accH[0][1] = MFMA16(a0, b1, accH[0][1]); accH[1][1] = MFMA16(a1, b1, accH[1][1]);
          accH[0][2] = MFMA16(a0, b2, accH[0][2]); accH[1][2] = MFMA16(a1, b2, accH[1][2]);
          accH[0][3] = MFMA16(a0, b3, accH[0][3]); accH[1][3] = MFMA16(a1, b3, accH[1][3]);
          __builtin_amdgcn_s_setprio(0);
          #pragma unroll
          for (int rt = 0; rt < 2; ++rt)
            #pragma unroll
            for (int i = 0; i < 4; ++i) {
              int lcol = (w * 4 + i) * 16 + lane15;
              float bb = f1bl[half * 256 + lcol];
              #pragma unroll
              for (int reg = 0; reg < 4; ++reg) {
                int row = rt * 16 + g * 4 + reg;
                float v = fmaxf(accH[rt][i][reg] + bb, 0.0f);
                stSbB(row, lcol, v);
              }
            }
        }
        __syncthreads();
        {
          const int B0 = FF2o + (w * 4) * 16 * 64 + half * 8 * 64;
          bf16x8 a0 = ldAfrag(Sb, 256, 0, 0, l);
          bf16x8 a1 = ldAfrag(Sb, 256, 1, 0, l);
          bf16x8 b0 = wsf[B0 + (0 * 16) * 64 + l];
          bf16x8 b1 = wsf[B0 + (1 * 16) * 64 + l];
          bf16x8 b2 = wsf[B0 + (2 * 16) * 64 + l];
          bf16x8 b3 = wsf[B0 + (3 * 16) * 64 + l];
          __builtin_amdgcn_s_setprio(1);
          #pragma unroll 1
          for (int s = 0; s < 7; ++s) {
            int sn = s + 1;
            bf16x8 na0 = ldAfrag(Sb, 256, 0, sn, l);
            bf16x8 na1 = ldAfrag(Sb, 256, 1, sn, l);
            bf16x8 nb0 = wsf[B0 + (0 * 16 + sn) * 64 + l];
            bf16x8 nb1 = wsf[B0 + (1 * 16 + sn) * 64 + l];
            bf16x8 nb2 = wsf[B0 + (2 * 16 + sn) * 64 + l];
            bf16x8 nb3 = wsf[B0 + (3 * 16 + sn) * 64 + l];
            acc2[0][0] = MFMA16(a0, b0, acc2[0][0]); acc2[1][0] = MFMA16(a1, b0, acc2[1][0]);
            acc2[0][1] = MFMA16(a0, b1, acc2[0][1]); acc2[1][1] = MFMA16(a1, b1, acc2[1][1]);
            acc2[0][2] = MFMA16(a0, b2, acc2[0][2]); acc2[1][2] = MFMA16(a1, b2, acc2[1][2]);
            acc2[0][3] = MFMA16(a0, b3, acc2[0][3]); acc2[1][3] = MFMA16(a1, b3, acc2[1][3]);
            a0 = na0; a1 = na1; b0 = nb0; b1 = nb1; b2 = nb2; b3 = nb3;
          }
          acc2[0][0] = MFMA16(a0, b0, acc2[0][0]); acc2[1][0] = MFMA16(a1, b0, acc2[1][0]);
          acc2[0][1] = MFMA16(a0, b1, acc2[0][1]); acc2[1][1] = MFMA16(a1, b1, acc2[1][1]);
          acc2[0][2] = MFMA16(a0, b2, acc2[0][2]); acc2[1][2] = MFMA16(a1, b2, acc2[1][2]);
          acc2[0][3] = MFMA16(a0, b3, acc2[0][3]); acc2[1][3] = MFMA16(a1, b3, acc2[1][3]);
          __builtin_amdgcn_s_setprio(0);
        }
        __syncthreads();
      }
      ln_apply(acc2, f2bl, l2s, l2b);
    }
  }

  // ================= S6: mean over views + MFMA out head =================
  {
    const int ptg = tid >> 5;
    const int lid = tid & 31;
    const int rb = ptg * 4;
    float gg[8];
    #pragma unroll
    for (int m = 0; m < 8; ++m) gg[m] = 0.0f;
    #pragma unroll
    for (int r4 = 0; r4 < 4; ++r4) {
      int row = rb + r4;
      int slot = lid ^ (row & 7);
      bf16x8 hv = *(const bf16x8*)(Ab + row * 256 + slot * 8);
      #pragma unroll
      for (int m = 0; m < 8; ++m) gg[m] += bf2f((unsigned short)hv[m]);
    }
    // stage pooled g (8 rows x 256, A-layout swizzled) into Sb; zero rows 8..15
    bf16x8 pk;
    #pragma unroll
    for (int m = 0; m < 8; ++m) pk[m] = (short)f2bf(gg[m] * 0.25f);
    {
      int slot = lid ^ (ptg & 7);
      *(bf16x8*)(Sb + ptg * 256 + slot * 8) = pk;
      bf16x8 z;
      #pragma unroll
      for (int m = 0; m < 8; ++m) z[m] = 0;
      int zr = 8 + ptg;
      int zslot = lid ^ (zr & 7);
      *(bf16x8*)(Sb + zr * 256 + zslot * 8) = z;
    }
    __syncthreads();
    f32x4 accO = vzero;
    #pragma unroll 1
    for (int s = 0; s < 8; ++s) {
      bf16x8 a = ldAfrag(Sb, 256, 0, s, l);
      bf16x8 b = wsf[FRAG_OUT + (w * 8 + s) * 64 + l];
      accO = MFMA16(a, b, accO);
    }
    int col = w * 16 + lane15;
    float ob = out_b[col];
    #pragma unroll
    for (int reg = 0; reg < 4; ++reg) {
      int row = g * 4 + reg;
      if (row < 8) {
        int p = pbase + row;
        if (p < M) outp[p * 64 + col] = accO[reg] + ob;
      }
    }
  }
}

extern "C" void kernel_launch(void* const* d_in, const int* in_sizes, int n_in,
                              void* d_out, int out_size, void* d_ws, size_t ws_size,
                              hipStream_t stream) {
  (void)n_in; (void)out_size;
  const float* xyz   = (const float*)d_in[0];
  const float* feat  = (const float*)d_in[1];
  const float* c2w   = (const float*)d_in[2];
  const float* intr  = (const float*)d_in[3];
  const int*   tids  = (const int*)d_in[4];
  const float* vemb  = (const float*)d_in[5];
  const float* pos_w = (const float*)d_in[6];
  const float* pos_b = (const float*)d_in[7];
  const float* fp_w  = (const float*)d_in[8];
  const float* fp_b  = (const float*)d_in[9];
  const float* qkv_w = (const float*)d_in[10];
  const float* qkv_b = (const float*)d_in[11];
  const float* ao_w  = (const float*)d_in[12];
  const float* ao_b  = (const float*)d_in[13];
  const float* ln1s  = (const float*)d_in[14];
  const float* ln1b  = (const float*)d_in[15];
  const float* ff1_w = (const float*)d_in[16];
  const float* ff1_b = (const float*)d_in[17];
  const float* ff2_w = (const float*)d_in[18];
  const float* ff2_b = (const float*)d_in[19];
  const float* ln2s  = (const float*)d_in[20];
  const float* ln2b  = (const float*)d_in[21];
  const float* out_w = (const float*)d_in[22];
  const float* out_b = (const float*)d_in[23];
  float* outp = (float*)d_out;

  if (ws_size < (size_t)FRAG_TOTAL * 16) return;

  unsigned short* wsp = (unsigned short*)d_ws;
  hipLaunchKernelGGL(prepack_kernel, dim3((FRAG_TOTAL + 255) / 256), dim3(256), 0, stream,
                     fp_w, qkv_w, ao_w, ff1_w, ff2_w, out_w, wsp);

  int M = in_sizes[0] / 3;
  int nblk = (M + PTS - 1) / PTS;
  hipLaunchKernelGGL(mvpa_kernel, dim3(nblk), dim3(256), 0, stream,
                     xyz, feat, c2w, intr, tids, vemb, pos_w, pos_b, fp_b, qkv_b,
                     ao_b, ln1s, ln1b, ff1_b, ff2_b, ln2s, ln2b, out_b,
                     wsp, outp, M);
}